// Round 2
// baseline (21527.638 us; speedup 1.0000x reference)
//
#include <hip/hip_runtime.h>

// 2-layer LSTM (B=4096, T=512, H=50) + FC head, fp32.
// Decomposition: 256 blocks x 16 batch. Block = 256 threads:
//   thread = (unit n in [0,64), k-quarter kq in [0,4)), lane = 4n+kq within wave
//   => DPP quad_perm reduces over the 4 kq lanes (same quad).
// H and K padded 50->64 with zero weights: dummy units produce h == 0.
// Weights live in VGPRs (192 regs), h0/h1 exchanged via small LDS (dbuf).
// Bias + x*W_ih0 are added AFTER the quad reduction (R1 bug: adding them
// pre-reduction counts them 4x).

#define LOG2E 1.44269504088896340736f

template <int CTRL>
__device__ __forceinline__ float dppf(float v) {
  return __int_as_float(
      __builtin_amdgcn_mov_dpp(__float_as_int(v), CTRL, 0xf, 0xf, true));
}

// sum over the 4 lanes of a quad (kq dimension)
__device__ __forceinline__ float qsum(float v) {
  v += dppf<0xB1>(v);  // quad_perm [1,0,3,2]  (xor 1)
  v += dppf<0x4E>(v);  // quad_perm [2,3,0,1]  (xor 2)
  return v;
}

__device__ __forceinline__ float sigm(float x) {
  return __builtin_amdgcn_rcpf(1.f + __builtin_amdgcn_exp2f(-LOG2E * x));
}
__device__ __forceinline__ float tanh_(float x) {
  // tanh(x) = 1 - 2/(exp(2x)+1)
  return 1.f - 2.f * __builtin_amdgcn_rcpf(1.f + __builtin_amdgcn_exp2f(2.f * LOG2E * x));
}
__device__ __forceinline__ void fma4(float4& a, float s, const float4& w) {
  a.x += s * w.x; a.y += s * w.y; a.z += s * w.z; a.w += s * w.w;
}

__global__ __launch_bounds__(256, 1) void lstm2_kernel(
    const float* __restrict__ x,
    const float* __restrict__ Wih0, const float* __restrict__ Whh0,
    const float* __restrict__ bih0, const float* __restrict__ bhh0,
    const float* __restrict__ Wih1, const float* __restrict__ Whh1,
    const float* __restrict__ bih1, const float* __restrict__ bhh1,
    const float* __restrict__ fcW, const float* __restrict__ fcb,
    float* __restrict__ out) {
  const int tid = threadIdx.x;
  const int n  = tid >> 2;  // padded unit 0..63 (>=50 dummy)
  const int kq = tid & 3;   // k-quarter
  const int bbase = blockIdx.x * 16;

  __shared__ float h0s[2][16][72];  // [parity][batch][padded unit 64 (+8 pad)]
  __shared__ float h1s[2][16][72];
  __shared__ float xs[16][64];      // x chunk: 16 batch x 64 timesteps

  // zero-init h buffers (parity 1 is read at t=0)
  for (int i = tid; i < 2 * 16 * 72; i += 256) {
    ((float*)h0s)[i] = 0.f;
    ((float*)h1s)[i] = 0.f;
  }

  // ---- load per-lane weight slices into registers ----
  // w*g[j][kk] = float4 over gates {i,f,g,o} at k = 16*kq + 4*j + kk
  float4 w0g[4][4], w1ig[4][4], w1hg[4][4];
  const bool nv = (n < 50);
#pragma unroll
  for (int j = 0; j < 4; ++j) {
#pragma unroll
    for (int kk = 0; kk < 4; ++kk) {
      const int k = 16 * kq + 4 * j + kk;
      const bool kv = nv && (k < 50);
      float4 a, b, c;
      a.x = kv ? Whh0[(0 * 50 + n) * 50 + k] : 0.f;
      a.y = kv ? Whh0[(1 * 50 + n) * 50 + k] : 0.f;
      a.z = kv ? Whh0[(2 * 50 + n) * 50 + k] : 0.f;
      a.w = kv ? Whh0[(3 * 50 + n) * 50 + k] : 0.f;
      b.x = kv ? Wih1[(0 * 50 + n) * 50 + k] : 0.f;
      b.y = kv ? Wih1[(1 * 50 + n) * 50 + k] : 0.f;
      b.z = kv ? Wih1[(2 * 50 + n) * 50 + k] : 0.f;
      b.w = kv ? Wih1[(3 * 50 + n) * 50 + k] : 0.f;
      c.x = kv ? Whh1[(0 * 50 + n) * 50 + k] : 0.f;
      c.y = kv ? Whh1[(1 * 50 + n) * 50 + k] : 0.f;
      c.z = kv ? Whh1[(2 * 50 + n) * 50 + k] : 0.f;
      c.w = kv ? Whh1[(3 * 50 + n) * 50 + k] : 0.f;
      w0g[j][kk] = a; w1ig[j][kk] = b; w1hg[j][kk] = c;
    }
  }
  float4 bb0, bb1, wx0;
  bb0.x = nv ? (bih0[0 * 50 + n] + bhh0[0 * 50 + n]) : 0.f;
  bb0.y = nv ? (bih0[1 * 50 + n] + bhh0[1 * 50 + n]) : 0.f;
  bb0.z = nv ? (bih0[2 * 50 + n] + bhh0[2 * 50 + n]) : 0.f;
  bb0.w = nv ? (bih0[3 * 50 + n] + bhh0[3 * 50 + n]) : 0.f;
  bb1.x = nv ? (bih1[0 * 50 + n] + bhh1[0 * 50 + n]) : 0.f;
  bb1.y = nv ? (bih1[1 * 50 + n] + bhh1[1 * 50 + n]) : 0.f;
  bb1.z = nv ? (bih1[2 * 50 + n] + bhh1[2 * 50 + n]) : 0.f;
  bb1.w = nv ? (bih1[3 * 50 + n] + bhh1[3 * 50 + n]) : 0.f;
  wx0.x = nv ? Wih0[0 * 50 + n] : 0.f;  // W_ih0 is (200,1)
  wx0.y = nv ? Wih0[1 * 50 + n] : 0.f;
  wx0.z = nv ? Wih0[2 * 50 + n] : 0.f;
  wx0.w = nv ? Wih0[3 * 50 + n] : 0.f;

  float c0[16], c1[16];
#pragma unroll
  for (int b = 0; b < 16; ++b) { c0[b] = 0.f; c1[b] = 0.f; }

  for (int t = 0; t < 512; ++t) {
    if ((t & 63) == 0) {  // stage next 64 timesteps of x
      __syncthreads();
      const int sb = tid >> 4, st = (tid & 15) << 2;
      *(float4*)&xs[sb][st] =
          *(const float4*)&x[(size_t)(bbase + sb) * 512 + t + st];
      __syncthreads();
    }
    const int rp = (t + 1) & 1;  // read prev-state parity
    const int wp = t & 1;        // write parity
    const int tm = t & 63;

    // ================= layer 0 =================
    // acc holds ONLY the k-partitioned matmul partials; bias + x-term are
    // added after qsum (adding them here counts them 4x across kq lanes).
    float4 acc[16];
#pragma unroll
    for (int b = 0; b < 16; ++b) acc[b] = make_float4(0.f, 0.f, 0.f, 0.f);
#pragma unroll
    for (int j = 0; j < 4; ++j) {
      const int koff = 16 * kq + 4 * j;
#pragma unroll
      for (int b = 0; b < 16; ++b) {
        const float4 hf = *(const float4*)&h0s[rp][b][koff];
        fma4(acc[b], hf.x, w0g[j][0]);
        fma4(acc[b], hf.y, w0g[j][1]);
        fma4(acc[b], hf.z, w0g[j][2]);
        fma4(acc[b], hf.w, w0g[j][3]);
      }
    }
#pragma unroll
    for (int b = 0; b < 16; ++b) {
      const float xv = xs[b][tm];
      float gi = sigm(qsum(acc[b].x) + bb0.x + xv * wx0.x);
      float gf = sigm(qsum(acc[b].y) + bb0.y + xv * wx0.y);
      float gg = tanh_(qsum(acc[b].z) + bb0.z + xv * wx0.z);
      float go = sigm(qsum(acc[b].w) + bb0.w + xv * wx0.w);
      const float c = gf * c0[b] + gi * gg;
      c0[b] = c;
      const float h = go * tanh_(c);
      if (kq == (b >> 2)) h0s[wp][b][n] = h;  // spread writes over kq lanes
    }
    __syncthreads();  // h0[t] ready

    // ================= layer 1 =================
#pragma unroll
    for (int b = 0; b < 16; ++b) acc[b] = make_float4(0.f, 0.f, 0.f, 0.f);
#pragma unroll
    for (int j = 0; j < 4; ++j) {
      const int koff = 16 * kq + 4 * j;
#pragma unroll
      for (int b = 0; b < 16; ++b) {
        const float4 hf0 = *(const float4*)&h0s[wp][b][koff];  // new h0
        const float4 hf1 = *(const float4*)&h1s[rp][b][koff];  // prev h1
        fma4(acc[b], hf0.x, w1ig[j][0]);
        fma4(acc[b], hf0.y, w1ig[j][1]);
        fma4(acc[b], hf0.z, w1ig[j][2]);
        fma4(acc[b], hf0.w, w1ig[j][3]);
        fma4(acc[b], hf1.x, w1hg[j][0]);
        fma4(acc[b], hf1.y, w1hg[j][1]);
        fma4(acc[b], hf1.z, w1hg[j][2]);
        fma4(acc[b], hf1.w, w1hg[j][3]);
      }
    }
#pragma unroll
    for (int b = 0; b < 16; ++b) {
      float gi = sigm(qsum(acc[b].x) + bb1.x);
      float gf = sigm(qsum(acc[b].y) + bb1.y);
      float gg = tanh_(qsum(acc[b].z) + bb1.z);
      float go = sigm(qsum(acc[b].w) + bb1.w);
      const float c = gf * c1[b] + gi * gg;
      c1[b] = c;
      const float h = go * tanh_(c);
      if (kq == (b >> 2)) h1s[wp][b][n] = h;
    }
    __syncthreads();  // h1[t] ready; also guards next step's WAR
  }

  // ---- FC head: out[b] = fc_b + sum_j fcW[j] * h1_last[b][j] ----
  if (tid < 16) {
    float s = fcb[0];
    for (int j = 0; j < 50; ++j) s += fcW[j] * h1s[1][tid][j];  // t=511 -> parity 1
    out[bbase + tid] = s;
  }
}

extern "C" void kernel_launch(void* const* d_in, const int* in_sizes, int n_in,
                              void* d_out, int out_size, void* d_ws, size_t ws_size,
                              hipStream_t stream) {
  const float* x    = (const float*)d_in[0];
  const float* Wih0 = (const float*)d_in[1];
  const float* Whh0 = (const float*)d_in[2];
  const float* bih0 = (const float*)d_in[3];
  const float* bhh0 = (const float*)d_in[4];
  const float* Wih1 = (const float*)d_in[5];
  const float* Whh1 = (const float*)d_in[6];
  const float* bih1 = (const float*)d_in[7];
  const float* bhh1 = (const float*)d_in[8];
  const float* fcW  = (const float*)d_in[9];
  const float* fcb  = (const float*)d_in[10];
  float* out = (float*)d_out;

  const int B = out_size;          // 4096
  const int blocks = B / 16;       // 256
  lstm2_kernel<<<dim3(blocks), dim3(256), 0, stream>>>(
      x, Wih0, Whh0, bih0, bhh0, Wih1, Whh1, bih1, bhh1, fcW, fcb, out);
}